// Round 4
// baseline (259.592 us; speedup 1.0000x reference)
//
#include <hip/hip_runtime.h>
#include <math.h>

// TIME_WARPING: not-a-knot cubic spline fit + warped resample, fused.
//
// Math (unchanged, harness-verified): spline system A M = rhs,
//   M1 = y0 - 2 y1 + y2 (exact); M_{S-2} = y_{S-3} - 2 y_{S-2} + y_{S-1} (exact)
//   M0 = 2 M1 - M2;  M_{S-1} = 2 M_{S-2} - M_{S-3}
//   interior: Toeplitz(1,4,1) inverse = conv with G(k) = (-1)^k r^|k|/(2 sqrt 3),
//   r = 2 - sqrt(3), truncated at W=8; interior M computed as 19-tap conv of y
//   with H = 6*(G (*) [1,-2,1]); edge region keeps exact f-based path with
//   boundary image corrections (ghost values v1/vS2).
//
// NEW this round (post-mortem: R0->R3 removed 17KB LDS, a barrier, 25% of VALU
// work and remapped pass D -- duration did NOT move => the binding constraint is
// memory-latency serialization in short-lived blocks, not occupancy/LDS/VALU):
//  * PERSISTENT blocks: grid = 1280 (5 blocks/CU x 256 CU), each block loops
//    over ~6-7 signals (bid += 1280).
//  * Register prefetch pipeline: next signal's 16KB is loaded into 4 float4
//    regs right after the current signal's LDS image is published; the ~900cy
//    HBM latency hides under pass C + pass D (~2000cy) of the current signal.
//  * lgkm-only barriers (s_waitcnt lgkmcnt(0) + raw s_barrier): __syncthreads
//    would drain vmcnt(0) (compiler-forced), killing the prefetch overlap and
//    stalling on NT-store drain every iteration. LDS correctness only needs
//    lgkm ordering. (T4: counted/partial waits across barriers.)
//  * Copy path (mask==0) folded into the loop, reads its image back from LDS.

#define SLEN 4096
#define WRAD 8
#define BLK  256
#define GRID 1280

typedef float f32x4 __attribute__((ext_vector_type(4)));

__device__ __forceinline__ void lbar() {
    // LDS-ordering barrier that does NOT drain vmcnt: in-flight global loads
    // (prefetch) and nontemporal stores stay outstanding across it.
    __builtin_amdgcn_sched_barrier(0);
    asm volatile("s_waitcnt lgkmcnt(0)" ::: "memory");
    __builtin_amdgcn_s_barrier();
    __builtin_amdgcn_sched_barrier(0);
}

__global__ __launch_bounds__(BLK, 5) void time_warp_kernel(
    const float* __restrict__ x,
    const float* __restrict__ scale,
    const int*   __restrict__ apply_mask,
    float* __restrict__ out,
    int C, int nsig)
{
    __shared__ float sy[SLEN];   // input signal          (16384 B)
    __shared__ float sm[SLEN];   // second derivatives M  (16384 B) => 32768 B

    const int t = threadIdx.x;

    // Green taps (compile-time folded)
    const float r = 0.26794919243112270f;  // 2 - sqrt(3)
    float G[WRAD + 1];
    G[0] = 0.28867513459481287f;           // 1 / (2 sqrt(3))
    #pragma unroll
    for (int k = 1; k <= WRAD; ++k) G[k] = -G[k - 1] * r;
    // H = 6 * (G convolved with [1,-2,1]) : 19-tap direct-on-y kernel
    float Hh[WRAD + 2];
    Hh[0] = 12.0f * (G[1] - G[0]);
    #pragma unroll
    for (int k = 1; k < WRAD; ++k) Hh[k] = 6.0f * (G[k - 1] - 2.0f * G[k] + G[k + 1]);
    Hh[WRAD]     = 6.0f * (G[WRAD - 1] - 2.0f * G[WRAD]);   // G[W+1] = 0
    Hh[WRAD + 1] = 6.0f * G[WRAD];
    const float log2r = -1.8999686269529532f;  // log2(2 - sqrt(3))

    int bid = blockIdx.x;
    f32x4 pf0, pf1, pf2, pf3;    // register prefetch buffer (one signal, 16KB/block)
    if (bid < nsig) {
        const f32x4* __restrict__ xi4 = (const f32x4*)(x + (size_t)bid * SLEN);
        pf0 = xi4[t];
        pf1 = xi4[t + BLK];
        pf2 = xi4[t + 2 * BLK];
        pf3 = xi4[t + 3 * BLK];
    }

    for (; bid < nsig; bid += GRID) {
        const int   b   = bid / C;
        const int   msk = apply_mask[b];
        const float sc  = scale[b];
        float* __restrict__ o = out + (size_t)bid * SLEN;

        // publish current signal to LDS (prior iteration's readers done)
        lbar();
        *(f32x4*)&sy[4 * t]        = pf0;   // compiler inserts vmcnt wait for pf
        *(f32x4*)&sy[4 * t + 1024] = pf1;
        *(f32x4*)&sy[4 * t + 2048] = pf2;
        *(f32x4*)&sy[4 * t + 3072] = pf3;
        lbar();                              // sy visible to all waves

        // issue next-signal prefetch; stays in flight through pass C + D
        const int nxt = bid + GRID;
        if (nxt < nsig) {
            const f32x4* __restrict__ xi4 = (const f32x4*)(x + (size_t)nxt * SLEN);
            pf0 = xi4[t];
            pf1 = xi4[t + BLK];
            pf2 = xi4[t + 2 * BLK];
            pf3 = xi4[t + 3 * BLK];
        }

        if (msk == 0) {
            // copy path: image is already in LDS, stream it out
            #pragma unroll
            for (int k = 0; k < 4; ++k) {
                f32x4 v = *(const f32x4*)&sy[4 * (t + BLK * k)];
                __builtin_nontemporal_store(v, &((f32x4*)o)[t + BLK * k]);
            }
            continue;   // block-uniform branch: no barrier divergence
        }

        // ---- pass C: M = conv(y) ----
        #pragma unroll
        for (int s = 0; s < 4; ++s) {
            const int j0 = 4 * t + 1024 * s;
            if (j0 >= 36 && j0 <= SLEN - 44) {
                // interior: pure 19-tap H-conv on y; 7 aligned b128 reads,
                // lane stride 16B (canonical conflict-free pattern).
                float wv[28];
                #pragma unroll
                for (int m = 0; m < 7; ++m)
                    *(float4*)&wv[4 * m] = *(const float4*)&sy[j0 - 12 + 4 * m];
                float mv[4];
                #pragma unroll
                for (int e = 0; e < 4; ++e) {
                    float acc = Hh[0] * wv[12 + e];
                    #pragma unroll
                    for (int k = 1; k <= WRAD + 1; ++k)
                        acc += Hh[k] * (wv[12 + e - k] + wv[12 + e + k]);
                    mv[e] = acc;
                }
                *(float4*)&sm[j0] = make_float4(mv[0], mv[1], mv[2], mv[3]);
            } else {
                // edge path (~19 threads/block): exact f-based conv with all
                // boundary rules + image corrections.
                const float M1  = sy[0]        - 2.0f * sy[1]        + sy[2];
                const float MS2 = sy[SLEN - 3] - 2.0f * sy[SLEN - 2] + sy[SLEN - 1];

                float v1 = 0.0f, vS2 = 0.0f;
                #pragma unroll
                for (int k = 1; k <= WRAD; ++k) {
                    const int ja = 1 + k;                        // 2..9
                    float fa = 6.0f * (sy[ja - 1] - 2.0f * sy[ja] + sy[ja + 1]);
                    if (ja == 2) fa -= M1;
                    v1 += G[k] * fa;
                    const int jb = SLEN - 2 - k;                 // S-3 .. S-10
                    float fb = 6.0f * (sy[jb - 1] - 2.0f * sy[jb] + sy[jb + 1]);
                    if (jb == SLEN - 3) fb -= MS2;
                    vS2 += G[k] * fb;
                }

                float wv[28];
                #pragma unroll
                for (int m = 0; m < 7; ++m) {
                    const int q = j0 - 12 + 4 * m;
                    float4 v = make_float4(0.0f, 0.0f, 0.0f, 0.0f);
                    if (q >= 0 && q <= SLEN - 4) v = *(const float4*)&sy[q];
                    *(float4*)&wv[4 * m] = v;
                }
                float fw[20];
                #pragma unroll
                for (int p = 0; p < 20; ++p) {
                    const int jj = j0 + p - 8;
                    float fv = 6.0f * (wv[p + 3] - 2.0f * wv[p + 4] + wv[p + 5]);
                    if (jj < 2 || jj > SLEN - 3) fv = 0.0f;
                    if (jj == 2)        fv -= M1;
                    if (jj == SLEN - 3) fv -= MS2;
                    fw[p] = fv;
                }
                float mv[4];
                #pragma unroll
                for (int e = 0; e < 4; ++e) {
                    float acc = G[0] * fw[8 + e];
                    #pragma unroll
                    for (int k = 1; k <= WRAD; ++k)
                        acc += G[k] * (fw[8 + e - k] + fw[8 + e + k]);
                    const int i = j0 + e;
                    if (i >= 2 && i <= 34) {
                        float cc = v1 * exp2f((float)(i - 1) * log2r);
                        acc += (i & 1) ? -cc : cc;
                    }
                    if (i >= SLEN - 36 && i <= SLEN - 3) {
                        float cc = vS2 * exp2f((float)(SLEN - 2 - i) * log2r);
                        acc += (i & 1) ? cc : -cc;
                    }
                    mv[e] = acc;
                }
                if (j0 == 0)        { mv[1] = M1;  mv[0] = 2.0f * M1  - mv[2]; }
                if (j0 == SLEN - 4) { mv[2] = MS2; mv[3] = 2.0f * MS2 - mv[1]; }
                *(float4*)&sm[j0] = make_float4(mv[0], mv[1], mv[2], mv[3]);
            }
        }
        lbar();                              // sm visible (sy still stable)

        // ---- pass D: warped evaluation, interleaved mapping j = t + 256*q ----
        #pragma unroll
        for (int q = 0; q < 16; ++q) {
            const int j = t + BLK * q;
            float w = fminf((float)j * sc, (float)(SLEN - 1));
            int idx = (int)w;
            if (idx > SLEN - 2) idx = SLEN - 2;
            const float tt  = w - (float)idx;
            const float y0  = sy[idx];
            const float y1  = sy[idx + 1];
            const float m0  = sm[idx];
            const float m1v = sm[idx + 1];
            const float bb = (y1 - y0) - (2.0f * m0 + m1v) * (1.0f / 6.0f);
            const float cc = 0.5f * m0;
            const float dd = (m1v - m0) * (1.0f / 6.0f);
            const float res = y0 + tt * (bb + tt * (cc + tt * dd));
            __builtin_nontemporal_store(res, &o[j]);
        }
    }
}

extern "C" void kernel_launch(void* const* d_in, const int* in_sizes, int n_in,
                              void* d_out, int out_size, void* d_ws, size_t ws_size,
                              hipStream_t stream) {
    const float* x     = (const float*)d_in[0];
    const float* scale = (const float*)d_in[1];
    const int*   mask  = (const int*)d_in[2];
    float*       out   = (float*)d_out;

    const int B     = in_sizes[1];            // 128
    const int total = in_sizes[0];            // B*C*S
    const int C     = total / (B * SLEN);     // 64
    const int nsig  = B * C;                  // 8192

    const int grid = (nsig < GRID) ? nsig : GRID;
    time_warp_kernel<<<grid, BLK, 0, stream>>>(x, scale, mask, out, C, nsig);
}

// Round 5
// 259.210 us; speedup vs baseline: 1.0015x; 1.0015x over previous
//
#include <hip/hip_runtime.h>
#include <math.h>

// TIME_WARPING: not-a-knot cubic spline fit + warped resample, fused.
//
// Math (identical to harness-verified versions): spline A M = rhs with
//   M1 = y0-2y1+y2 (exact), MS2 = y[S-3]-2y[S-2]+y[S-1] (exact),
//   M0 = 2M1-M2, M[S-1] = 2MS2-M[S-3]; interior Toeplitz(1,4,1) inverse =
//   conv with G(k) = (-1)^k r^k/(2 sqrt3), r = 2-sqrt(3), truncated W=8.
//   Interior M == 19-tap conv of y with H = 6*(G (*) [1,-2,1]).
//   Near-boundary M: f-based conv + image corrections (ghost v1/vS2).
//
// R5 structure (post-mortem R0-R4: occupancy, conflicts, and latency-hiding all
// falsified; derived model says LDS unit is the busiest pipe at ~55-65%):
//  * sm[] ELIMINATED. Pass C merged into pass D: each thread computes the <=6
//    M values its 4 consecutive outputs need, in registers, from ONE 24-float
//    LDS window (sequential scalar reads -> ds_read2_b32 merge). Per-output
//    m0/m1 picked by compile-time-indexed cndmask chains (no runtime reg
//    indexing -> no scratch). LDS traffic -50%, one barrier removed, LDS 16KB.
//  * Edge / clamped outputs -> noinline cold path (exact f-based conv with
//    boundary rules + image corrections); fully-clamped threads (idx0==S-2)
//    use a 1-conv fast path. Cold path is <=3 waves/signal, execz-skipped.
//  * Copy path (mask==0) before staging: pure global->global float4 NT copy.

#define SLEN 4096
#define WRAD 8
#define BLK  256

typedef float f32x4 __attribute__((ext_vector_type(4)));

// ---- cold path: exact f-based M for near-boundary / clamped outputs ----
__device__ __attribute__((noinline))
f32x4 edge_eval(const float* __restrict__ sy, int j0, float sc)
{
    const float log2r = -1.8999686269529532f;  // log2(2 - sqrt(3))
    const float r = 0.26794919243112270f;
    float G[WRAD + 1];
    G[0] = 0.28867513459481287f;               // 1/(2 sqrt 3)
    #pragma unroll
    for (int k = 1; k <= WRAD; ++k) G[k] = -G[k - 1] * r;

    const float M1  = sy[0]        - 2.0f * sy[1]        + sy[2];
    const float MS2 = sy[SLEN - 3] - 2.0f * sy[SLEN - 2] + sy[SLEN - 1];

    // ghost values for image corrections
    float v1 = 0.0f, vS2 = 0.0f;
    #pragma unroll
    for (int k = 1; k <= WRAD; ++k) {
        const int ja = 1 + k;                               // 2..9
        float fa = 6.0f * (sy[ja - 1] - 2.0f * sy[ja] + sy[ja + 1]);
        if (ja == 2) fa -= M1;
        v1 += G[k] * fa;
        const int jb = SLEN - 2 - k;                        // S-3..S-10
        float fb = 6.0f * (sy[jb - 1] - 2.0f * sy[jb] + sy[jb + 1]);
        if (jb == SLEN - 3) fb -= MS2;
        vS2 += G[k] * fb;
    }

    auto Mconv = [&](int i) -> float {                      // valid 2 <= i <= S-3
        float acc = 0.0f;
        #pragma unroll
        for (int k = -WRAD; k <= WRAD; ++k) {
            const int j = i + k;
            float fj = 0.0f;
            if (j >= 2 && j <= SLEN - 3) {
                fj = 6.0f * (sy[j - 1] - 2.0f * sy[j] + sy[j + 1]);
                if (j == 2)        fj -= M1;
                if (j == SLEN - 3) fj -= MS2;
            }
            acc += G[k < 0 ? -k : k] * fj;
        }
        if (i <= 34) {
            float cc = v1 * exp2f((float)(i - 1) * log2r);
            acc += (i & 1) ? -cc : cc;
        }
        if (i >= SLEN - 36) {
            float cc = vS2 * exp2f((float)(SLEN - 2 - i) * log2r);
            acc += (i & 1) ? cc : -cc;
        }
        return acc;
    };
    auto Mfull = [&](int i) -> float {
        if (i == 1)        return M1;
        if (i == SLEN - 2) return MS2;
        if (i == 0)        return 2.0f * M1  - Mconv(2);
        if (i == SLEN - 1) return 2.0f * MS2 - Mconv(SLEN - 3);
        return Mconv(i);
    };

    f32x4 rv;
    // fully-clamped fast path: all 4 outputs land in the last interval
    float w0 = fminf((float)j0 * sc, (float)(SLEN - 1));
    int  id0 = (int)w0; if (id0 > SLEN - 2) id0 = SLEN - 2;
    if (id0 == SLEN - 2) {
        const float m0 = MS2;
        const float m1 = 2.0f * MS2 - Mconv(SLEN - 3);
        const float y0 = sy[SLEN - 2], y1 = sy[SLEN - 1];
        const float bb = (y1 - y0) - (2.0f * m0 + m1) * (1.0f / 6.0f);
        const float cf = 0.5f * m0;
        const float dd = (m1 - m0) * (1.0f / 6.0f);
        #pragma unroll
        for (int e = 0; e < 4; ++e) {
            float w  = fminf((float)(j0 + e) * sc, (float)(SLEN - 1));
            float tt = w - (float)(SLEN - 2);
            rv[e] = y0 + tt * (bb + tt * (cf + tt * dd));
        }
        return rv;
    }
    #pragma unroll
    for (int e = 0; e < 4; ++e) {
        float w  = fminf((float)(j0 + e) * sc, (float)(SLEN - 1));
        int  id  = (int)w; if (id > SLEN - 2) id = SLEN - 2;
        const float tt = w - (float)id;
        const float m0 = Mfull(id);
        const float m1 = Mfull(id + 1);
        const float y0 = sy[id], y1 = sy[id + 1];
        const float bb = (y1 - y0) - (2.0f * m0 + m1) * (1.0f / 6.0f);
        const float cf = 0.5f * m0;
        const float dd = (m1 - m0) * (1.0f / 6.0f);
        rv[e] = y0 + tt * (bb + tt * (cf + tt * dd));
    }
    return rv;
}

__global__ __launch_bounds__(BLK, 5) void time_warp_kernel(
    const float* __restrict__ x,
    const float* __restrict__ scale,
    const int*   __restrict__ apply_mask,
    float* __restrict__ out,
    int C)
{
    __shared__ float sy[SLEN];                 // 16384 B total LDS

    const int bid = blockIdx.x;                // = b*C + c
    const int b   = bid / C;
    const int t   = threadIdx.x;
    const float* __restrict__ xin = x   + (size_t)bid * SLEN;
    float*       __restrict__ o   = out + (size_t)bid * SLEN;

    // per-sample apply decision (block-uniform, before any barrier)
    if (apply_mask[b] == 0) {
        const f32x4* __restrict__ xi4 = (const f32x4*)xin;
        f32x4*       __restrict__ o4  = (f32x4*)o;
        #pragma unroll
        for (int k = 0; k < 4; ++k) {
            f32x4 v = xi4[t + BLK * k];
            __builtin_nontemporal_store(v, &o4[t + BLK * k]);
        }
        return;
    }

    // stage y into LDS (coalesced float4 -> ds_write_b128)
    {
        const float4* __restrict__ xi4 = (const float4*)xin;
        #pragma unroll
        for (int k = 0; k < 4; ++k)
            *(float4*)&sy[4 * (t + BLK * k)] = xi4[t + BLK * k];
    }
    __syncthreads();                           // the ONLY barrier

    const float sc = scale[b];

    // H = 6*(G (*) [1,-2,1]) taps (compile-time folded)
    const float r = 0.26794919243112270f;
    float G[WRAD + 1];
    G[0] = 0.28867513459481287f;
    #pragma unroll
    for (int k = 1; k <= WRAD; ++k) G[k] = -G[k - 1] * r;
    float Hh[WRAD + 2];
    Hh[0] = 12.0f * (G[1] - G[0]);
    #pragma unroll
    for (int k = 1; k < WRAD; ++k) Hh[k] = 6.0f * (G[k - 1] - 2.0f * G[k] + G[k + 1]);
    Hh[WRAD]     = 6.0f * (G[WRAD - 1] - 2.0f * G[WRAD]);
    Hh[WRAD + 1] = 6.0f * G[WRAD];

    #pragma unroll
    for (int s = 0; s < 4; ++s) {
        const int j0 = 4 * t + 1024 * s;       // 4 consecutive outputs / thread
        const int idx0 = (int)fminf((float)j0 * sc, (float)(SLEN - 1));
        f32x4 res;

        if (idx0 >= 35 && idx0 <= SLEN - 42) {
            // ---- hot interior path: everything in registers ----
            // y window [idx0-9, idx0+14]; sequential scalar reads from one
            // base -> DS combiner emits ds_read2_b32 pairs.
            const float* __restrict__ wp = &sy[idx0 - 9];
            float wv[24];
            #pragma unroll
            for (int m = 0; m < 24; ++m) wv[m] = wp[m];

            // M[idx0 .. idx0+5] via 19-tap H-conv (exact same math as before)
            float Ms[6];
            #pragma unroll
            for (int ii = 0; ii < 6; ++ii) {
                float acc = Hh[0] * wv[9 + ii];
                #pragma unroll
                for (int k = 1; k <= WRAD + 1; ++k)
                    acc += Hh[k] * (wv[9 + ii - k] + wv[9 + ii + k]);
                Ms[ii] = acc;
            }

            #pragma unroll
            for (int e = 0; e < 4; ++e) {
                const float w  = (float)(j0 + e) * sc;   // no clamp needed here
                const int   id = (int)w;                 // idx0 <= id <= idx0+4
                const float tt = w - (float)id;
                const int   d  = id - idx0;              // 0..4
                // compile-time-indexed select chain (no runtime reg indexing)
                float m0 = Ms[0], m1 = Ms[1];
                if (d >= 1) { m0 = Ms[1]; m1 = Ms[2]; }
                if (d >= 2) { m0 = Ms[2]; m1 = Ms[3]; }
                if (d >= 3) { m0 = Ms[3]; m1 = Ms[4]; }
                if (d >= 4) { m0 = Ms[4]; m1 = Ms[5]; }
                const float y0 = sy[id], y1 = sy[id + 1];
                const float bb = (y1 - y0) - (2.0f * m0 + m1) * (1.0f / 6.0f);
                const float cf = 0.5f * m0;
                const float dd = (m1 - m0) * (1.0f / 6.0f);
                res[e] = y0 + tt * (bb + tt * (cf + tt * dd));
            }
        } else {
            // cold path: near-boundary / clamped (execz-skipped when no lane)
            res = edge_eval(sy, j0, sc);
        }

        __builtin_nontemporal_store(res, (f32x4*)&o[j0]);
    }
}

extern "C" void kernel_launch(void* const* d_in, const int* in_sizes, int n_in,
                              void* d_out, int out_size, void* d_ws, size_t ws_size,
                              hipStream_t stream) {
    const float* x     = (const float*)d_in[0];
    const float* scale = (const float*)d_in[1];
    const int*   mask  = (const int*)d_in[2];
    float*       out   = (float*)d_out;

    const int B     = in_sizes[1];            // 128
    const int total = in_sizes[0];            // B*C*S
    const int C     = total / (B * SLEN);     // 64
    const int nblk  = B * C;                  // 8192

    time_warp_kernel<<<nblk, BLK, 0, stream>>>(x, scale, mask, out, C);
}